// Round 10
// baseline (71.448 us; speedup 1.0000x reference)
//
#include <hip/hip_runtime.h>
#include <hip/hip_bf16.h>

#define N_NODES 4096
#define F_IN    128
#define HEADS   4
#define FTOT    128
#define NSPLIT  8
#define NRANGE  (N_NODES / NSPLIT)   // 512
#define NSTEP   (NRANGE / 64)        // 8
#define HPB     512                  // k_pre hp blocks (8 nodes each)
#define BITB    1024                 // k_pre bit-transpose blocks (64 cols x 256 rows)
#define L2E     1.4426950408889634f

typedef __attribute__((ext_vector_type(8)))  short  short8v;
typedef __attribute__((ext_vector_type(16))) float  float16v;

static __device__ __forceinline__ unsigned f2bfu(float f) {
    union { __hip_bfloat16 h; unsigned short u; } cv;
    cv.h = __float2bfloat16(f);
    return (unsigned)cv.u;
}
// packed RNE f32x2 -> bf16x2 (single HW instr; scalar __float2bfloat16 is a
// multi-instruction sequence and was the round-9 VALU bloat)
static __device__ __forceinline__ unsigned cvt_pk_bf16(float lo, float hi) {
    unsigned r;
    asm("v_cvt_pk_bf16_f32 %0, %1, %2" : "=v"(r) : "v"(lo), "v"(hi));
    return r;
}

// ---------------- kernel 1: heterogeneous pre-pass (unchanged from r9) ----------------
__global__ __launch_bounds__(256)
void k_pre(const float* __restrict__ x, const float* __restrict__ W,
           const float* __restrict__ att_src, const float* __restrict__ att_dst,
           const float* __restrict__ adj,
           unsigned short* __restrict__ hpt, float* __restrict__ ast,
           float* __restrict__ adt, unsigned* __restrict__ abits)
{
    const int t = threadIdx.x;
    if (blockIdx.x < HPB) {
        __shared__ alignas(16) float    xs[8 * F_IN];
        __shared__ alignas(16) unsigned hs[F_IN * 4];
        __shared__ float ssa[4][8], ssd[4][8];
        const int sub = t >> 7;
        const int tt  = t & 127;
        const int i0  = blockIdx.x * 8;
        reinterpret_cast<float4*>(xs)[t] =
            reinterpret_cast<const float4*>(x + (size_t)i0 * F_IN)[t];
        __syncthreads();

        const float4* W4  = reinterpret_cast<const float4*>(W + tt * F_IN);
        const float4* xs4 = reinterpret_cast<const float4*>(xs + sub * 4 * F_IN);
        float a0 = 0.f, a1 = 0.f, a2 = 0.f, a3 = 0.f;
#pragma unroll
        for (int k = 0; k < F_IN / 4; ++k) {
            const float4 w  = W4[k];
            const float4 v0 = xs4[k], v1 = xs4[32 + k], v2 = xs4[64 + k], v3 = xs4[96 + k];
            a0 = fmaf(w.x, v0.x, a0); a0 = fmaf(w.y, v0.y, a0); a0 = fmaf(w.z, v0.z, a0); a0 = fmaf(w.w, v0.w, a0);
            a1 = fmaf(w.x, v1.x, a1); a1 = fmaf(w.y, v1.y, a1); a1 = fmaf(w.z, v1.z, a1); a1 = fmaf(w.w, v1.w, a1);
            a2 = fmaf(w.x, v2.x, a2); a2 = fmaf(w.y, v2.y, a2); a2 = fmaf(w.z, v2.z, a2); a2 = fmaf(w.w, v2.w, a2);
            a3 = fmaf(w.x, v3.x, a3); a3 = fmaf(w.y, v3.y, a3); a3 = fmaf(w.z, v3.z, a3); a3 = fmaf(w.w, v3.w, a3);
        }
        hs[tt * 4 + sub * 2 + 0] = f2bfu(a0) | (f2bfu(a1) << 16);
        hs[tt * 4 + sub * 2 + 1] = f2bfu(a2) | (f2bfu(a3) << 16);

        const float asv = att_src[tt], adv = att_dst[tt];
        float s0 = a0 * asv, s1 = a1 * asv, s2 = a2 * asv, s3 = a3 * asv;
        float d0 = a0 * adv, d1 = a1 * adv, d2 = a2 * adv, d3 = a3 * adv;
#pragma unroll
        for (int s = 16; s; s >>= 1) {
            s0 += __shfl_xor(s0, s); s1 += __shfl_xor(s1, s);
            s2 += __shfl_xor(s2, s); s3 += __shfl_xor(s3, s);
            d0 += __shfl_xor(d0, s); d1 += __shfl_xor(d1, s);
            d2 += __shfl_xor(d2, s); d3 += __shfl_xor(d3, s);
        }
        if ((tt & 31) == 0) {
            const int hh = tt >> 5;
            ssa[hh][sub * 4 + 0] = s0 * L2E; ssa[hh][sub * 4 + 1] = s1 * L2E;
            ssa[hh][sub * 4 + 2] = s2 * L2E; ssa[hh][sub * 4 + 3] = s3 * L2E;
            ssd[hh][sub * 4 + 0] = d0 * L2E; ssd[hh][sub * 4 + 1] = d1 * L2E;
            ssd[hh][sub * 4 + 2] = d2 * L2E; ssd[hh][sub * 4 + 3] = d3 * L2E;
        }
        __syncthreads();
        if (t < 128)
            *reinterpret_cast<uint4*>(hpt + (size_t)t * N_NODES + i0) =
                *reinterpret_cast<const uint4*>(&hs[t * 4]);
        if (t < 64) {
            const int sd = t >> 5, hh = (t >> 3) & 3, nn = t & 7;
            const float v = sd ? ssd[hh][nn] : ssa[hh][nn];
            (sd ? adt : ast)[hh * N_NODES + i0 + nn] = v;
        }
    } else {
        __shared__ alignas(16) unsigned short lb[64 * 16];
        const int sblk  = blockIdx.x - HPB;
        const int strip = sblk & 63;
        const int chunk = sblk >> 6;
        const int c0    = strip * 64;
        const int r0    = chunk * 256;
        const int q     = t & 15;
        const int p     = t >> 4;
        const float4* adj4 = reinterpret_cast<const float4*>(adj);

        float4 v[16];
#pragma unroll
        for (int it = 0; it < 16; ++it)
            v[it] = adj4[(size_t)(r0 + p * 16 + it) * (N_NODES / 4) + (c0 >> 2) + q];
        unsigned mk0 = 0, mk1 = 0, mk2 = 0, mk3 = 0;
#pragma unroll
        for (int it = 0; it < 16; ++it) {
            mk0 |= (v[it].x != 0.f) ? (1u << it) : 0u;
            mk1 |= (v[it].y != 0.f) ? (1u << it) : 0u;
            mk2 |= (v[it].z != 0.f) ? (1u << it) : 0u;
            mk3 |= (v[it].w != 0.f) ? (1u << it) : 0u;
        }
        lb[(4 * q + 0) * 16 + p] = (unsigned short)mk0;
        lb[(4 * q + 1) * 16 + p] = (unsigned short)mk1;
        lb[(4 * q + 2) * 16 + p] = (unsigned short)mk2;
        lb[(4 * q + 3) * 16 + p] = (unsigned short)mk3;
        __syncthreads();
        const unsigned* lb32 = reinterpret_cast<const unsigned*>(lb);
#pragma unroll
        for (int j = 0; j < 2; ++j) {
            const int w = t + j * 256;
            const int m = w >> 3, col = w & 7;
            abits[(size_t)(c0 + m) * (N_NODES / 32) + chunk * 8 + col] = lb32[w];
        }
    }
}

// ---------------- kernel 2: dense fused MFMA aggregation ----------------
// 1024 blocks (4/CU): 32 m-rows x 4 waves (wave=head) x 512-n split.
// Double-buffered hps, one barrier/step, load-early/write-late staging.
// tau accumulated by a second MFMA against a ones-B fragment.
__global__ __launch_bounds__(256, 4)
void k_main(const unsigned short* __restrict__ hpt, const float* __restrict__ ast,
            const float* __restrict__ adt, const unsigned* __restrict__ abits,
            float* __restrict__ z_part, float* __restrict__ taup)
{
    __shared__ alignas(16) unsigned short hps[2][128 * 64]; // 2 x 16 KB, swizzled
    __shared__ alignas(16) unsigned       bts[32 * 16];     // [m][64 B n-bits], 2 KB
    char* hps_c = reinterpret_cast<char*>(hps);
    char* bts_c = reinterpret_cast<char*>(bts);

    const int t     = threadIdx.x;
    const int wv    = t >> 6;                  // head
    const int l     = t & 63;
    const int np    = l >> 5;
    const int lm    = l & 31;
    const int mt    = blockIdx.x >> 3;
    const int split = blockIdx.x & 7;
    const int m0    = mt * 32;
    const int nb0   = split * NRANGE;

    // stage bits tile [32 m][64 B] (swizzled, 16B-preserving XOR)
    if (t < 128) {
        const int m = t >> 2;
        uint4 v = *reinterpret_cast<const uint4*>(
            abits + (size_t)(m0 + m) * (N_NODES / 32) + split * 16 + (t & 3) * 4);
        *reinterpret_cast<uint4*>(bts_c + (((unsigned)(t * 16)) ^ ((unsigned)(m & 3) << 4))) = v;
    }

    auto load_hp = [&](int step, uint4* v) {
        const int nb = nb0 + step * 64;
#pragma unroll
        for (int j = 0; j < 4; ++j) {
            const int lin = t + j * 256;
            const int f = lin >> 3, part = lin & 7;
            v[j] = *reinterpret_cast<const uint4*>(hpt + (size_t)f * N_NODES + nb + part * 8);
        }
    };
    auto write_hp = [&](int sel, const uint4* v) {
#pragma unroll
        for (int j = 0; j < 4; ++j) {
            const int lin = t + j * 256;
            const int f = lin >> 3;
            const unsigned byte = ((unsigned)(lin * 16)) ^ ((unsigned)(f & 7) << 4);
            *reinterpret_cast<uint4*>(hps_c + sel * 16384 + byte) = v[j];
        }
    };

    const float adm = adt[wv * N_NODES + m0 + lm];
    const float* asw = ast + wv * N_NODES + nb0;

    float16v acc, acct;
#pragma unroll
    for (int r = 0; r < 16; ++r) { acc[r] = 0.f; acct[r] = 0.f; }
    union { short8v v; unsigned u[4]; } ones;
#pragma unroll
    for (int j = 0; j < 4; ++j) ones.u[j] = 0x3F803F80u;   // bf16 1.0 x2

    {
        uint4 pre[4];
        load_hp(0, pre);
        write_hp(0, pre);
    }
    __syncthreads();

    for (int step = 0; step < NSTEP; ++step) {
        const int sel = step & 1;
        const bool more = (step + 1) < NSTEP;
        uint4 nxt[4];
        if (more) load_hp(step + 1, nxt);   // issue early; write after compute

        const unsigned baddr = ((unsigned)(lm * 64 + step * 8)) ^ ((unsigned)(lm & 3) << 4);
        const unsigned long long b64 =
            *reinterpret_cast<const unsigned long long*>(bts_c + baddr);
        const float* ap0 = asw + step * 64;
#pragma unroll
        for (int q = 0; q < 4; ++q) {
            const float4 a0 = *reinterpret_cast<const float4*>(ap0 + q * 16 + np * 8);
            const float4 a1 = *reinterpret_cast<const float4*>(ap0 + q * 16 + np * 8 + 4);
            const unsigned bb = (unsigned)(b64 >> ((2 * q + np) * 8)) & 0xFFu;
            auto wq = [&](float a, unsigned bit) {
                const float c  = a + adm;
                const float ex = exp2f(fmaxf(0.2f * c, c));
                return (bb & bit) ? ex : 0.f;
            };
            const float w0 = wq(a0.x, 1u),  w1 = wq(a0.y, 2u);
            const float w2 = wq(a0.z, 4u),  w3 = wq(a0.w, 8u);
            const float w4 = wq(a1.x, 16u), w5 = wq(a1.y, 32u);
            const float w6 = wq(a1.z, 64u), w7 = wq(a1.w, 128u);
            union { short8v v; unsigned u[4]; } af;
            af.u[0] = cvt_pk_bf16(w0, w1);
            af.u[1] = cvt_pk_bf16(w2, w3);
            af.u[2] = cvt_pk_bf16(w4, w5);
            af.u[3] = cvt_pk_bf16(w6, w7);
            const unsigned bofs =
                ((unsigned)((wv * 32 + lm) * 128 + (q * 16 + np * 8) * 2)) ^ ((unsigned)(lm & 7) << 4);
            const short8v bv = *reinterpret_cast<const short8v*>(hps_c + sel * 16384 + bofs);
            acc  = __builtin_amdgcn_mfma_f32_32x32x16_bf16(af.v, bv, acc, 0, 0, 0);
            acct = __builtin_amdgcn_mfma_f32_32x32x16_bf16(af.v, ones.v, acct, 0, 0, 0);
        }
        if (more) write_hp(sel ^ 1, nxt);
        __syncthreads();
    }

    // tau: every col of acct holds the row-sum; lanes lm==0 (np=0,1) cover all 32 rows
    if (lm == 0) {
#pragma unroll
        for (int r = 0; r < 16; ++r) {
            const int row = (r & 3) + 8 * (r >> 2) + 4 * np;
            taup[((size_t)split * HEADS + wv) * N_NODES + m0 + row] = acct[r];
        }
    }
    float* zp = z_part + (size_t)split * N_NODES * FTOT;
#pragma unroll
    for (int r = 0; r < 16; ++r) {
        const int row = (r & 3) + 8 * (r >> 2) + 4 * np;
        zp[(size_t)(m0 + row) * FTOT + wv * 32 + lm] = acc[r];
    }
}

// ---------------- kernel 3: merge splits, divide by tau, add bias ----------------
__global__ __launch_bounds__(256)
void k_fin(const float* __restrict__ z_part, const float* __restrict__ taup,
           const float* __restrict__ bias, float* __restrict__ out)
{
    const int idx = blockIdx.x * 256 + threadIdx.x;
    const int m = idx >> 5, f4 = idx & 31, h = f4 >> 3;
    const float4* zp4 = reinterpret_cast<const float4*>(z_part);
    float4 z = make_float4(0.f, 0.f, 0.f, 0.f);
    float ts = 0.f;
#pragma unroll
    for (int s = 0; s < NSPLIT; ++s) {
        const float4 zs = zp4[(size_t)s * N_NODES * (FTOT / 4) + idx];
        z.x += zs.x; z.y += zs.y; z.z += zs.z; z.w += zs.w;
        ts += taup[((size_t)s * HEADS + h) * N_NODES + m];
    }
    const float inv = 1.f / ts;
    const float4 b = reinterpret_cast<const float4*>(bias)[f4];
    float4 o;
    o.x = z.x * inv + b.x; o.y = z.y * inv + b.y;
    o.z = z.z * inv + b.z; o.w = z.w * inv + b.w;
    reinterpret_cast<float4*>(out)[idx] = o;
}

extern "C" void kernel_launch(void* const* d_in, const int* in_sizes, int n_in,
                              void* d_out, int out_size, void* d_ws, size_t ws_size,
                              hipStream_t stream) {
    const float* x       = (const float*)d_in[0];
    const float* adj     = (const float*)d_in[1];
    const float* weight  = (const float*)d_in[2];
    const float* att_src = (const float*)d_in[3];
    const float* att_dst = (const float*)d_in[4];
    const float* bias    = (const float*)d_in[5];
    float* out = (float*)d_out;

    // ws: hpt 1MB | ast 64KB | adt 64KB | abits 2MB | z_part 16MB | taup 512KB
    unsigned short* hpt = (unsigned short*)d_ws;
    float* ast = (float*)(hpt + (size_t)FTOT * N_NODES);
    float* adt = ast + (size_t)HEADS * N_NODES;
    unsigned* abits = (unsigned*)(adt + (size_t)HEADS * N_NODES);
    float* z_part = (float*)(abits + (size_t)N_NODES * (N_NODES / 32));
    float* taup = z_part + (size_t)NSPLIT * N_NODES * FTOT;

    k_pre <<<HPB + BITB, 256, 0, stream>>>(x, weight, att_src, att_dst, adj,
                                           hpt, ast, adt, abits);
    k_main<<<(N_NODES / 32) * NSPLIT, 256, 0, stream>>>(hpt, ast, adt, abits,
                                                        z_part, taup);
    k_fin <<<N_NODES * (FTOT / 4) / 256, 256, 0, stream>>>(z_part, taup, bias, out);
}

// Round 11
// 54.302 us; speedup vs baseline: 1.3158x; 1.3158x over previous
//
#include <hip/hip_runtime.h>
#include <hip/hip_bf16.h>

#define N_NODES 4096
#define F_IN    128
#define HEADS   4
#define FTOT    128
#define NSPLIT  8
#define NRANGE  (N_NODES / NSPLIT)   // 512
#define NSTEP   (NRANGE / 64)        // 8
#define HPB     512
#define BITB    1024
#define L2E     1.4426950408889634f

typedef __attribute__((ext_vector_type(8)))  short  short8v;
typedef __attribute__((ext_vector_type(16))) float  float16v;

static __device__ __forceinline__ unsigned f2bfu(float f) {
    union { __hip_bfloat16 h; unsigned short u; } cv;
    cv.h = __float2bfloat16(f);
    return (unsigned)cv.u;
}
static __device__ __forceinline__ unsigned cvt_pk_bf16(float lo, float hi) {
    unsigned r;
    asm("v_cvt_pk_bf16_f32 %0, %1, %2" : "=v"(r) : "v"(lo), "v"(hi));
    return r;
}

// ---------------- kernel 1: heterogeneous pre-pass (unchanged, verified) ----------------
__global__ __launch_bounds__(256)
void k_pre(const float* __restrict__ x, const float* __restrict__ W,
           const float* __restrict__ att_src, const float* __restrict__ att_dst,
           const float* __restrict__ adj,
           unsigned short* __restrict__ hpt, float* __restrict__ ast,
           float* __restrict__ adt, unsigned* __restrict__ abits)
{
    const int t = threadIdx.x;
    if (blockIdx.x < HPB) {
        __shared__ alignas(16) float    xs[8 * F_IN];
        __shared__ alignas(16) unsigned hs[F_IN * 4];
        __shared__ float ssa[4][8], ssd[4][8];
        const int sub = t >> 7;
        const int tt  = t & 127;
        const int i0  = blockIdx.x * 8;
        reinterpret_cast<float4*>(xs)[t] =
            reinterpret_cast<const float4*>(x + (size_t)i0 * F_IN)[t];
        __syncthreads();

        const float4* W4  = reinterpret_cast<const float4*>(W + tt * F_IN);
        const float4* xs4 = reinterpret_cast<const float4*>(xs + sub * 4 * F_IN);
        float a0 = 0.f, a1 = 0.f, a2 = 0.f, a3 = 0.f;
#pragma unroll
        for (int k = 0; k < F_IN / 4; ++k) {
            const float4 w  = W4[k];
            const float4 v0 = xs4[k], v1 = xs4[32 + k], v2 = xs4[64 + k], v3 = xs4[96 + k];
            a0 = fmaf(w.x, v0.x, a0); a0 = fmaf(w.y, v0.y, a0); a0 = fmaf(w.z, v0.z, a0); a0 = fmaf(w.w, v0.w, a0);
            a1 = fmaf(w.x, v1.x, a1); a1 = fmaf(w.y, v1.y, a1); a1 = fmaf(w.z, v1.z, a1); a1 = fmaf(w.w, v1.w, a1);
            a2 = fmaf(w.x, v2.x, a2); a2 = fmaf(w.y, v2.y, a2); a2 = fmaf(w.z, v2.z, a2); a2 = fmaf(w.w, v2.w, a2);
            a3 = fmaf(w.x, v3.x, a3); a3 = fmaf(w.y, v3.y, a3); a3 = fmaf(w.z, v3.z, a3); a3 = fmaf(w.w, v3.w, a3);
        }
        hs[tt * 4 + sub * 2 + 0] = f2bfu(a0) | (f2bfu(a1) << 16);
        hs[tt * 4 + sub * 2 + 1] = f2bfu(a2) | (f2bfu(a3) << 16);

        const float asv = att_src[tt], adv = att_dst[tt];
        float s0 = a0 * asv, s1 = a1 * asv, s2 = a2 * asv, s3 = a3 * asv;
        float d0 = a0 * adv, d1 = a1 * adv, d2 = a2 * adv, d3 = a3 * adv;
#pragma unroll
        for (int s = 16; s; s >>= 1) {
            s0 += __shfl_xor(s0, s); s1 += __shfl_xor(s1, s);
            s2 += __shfl_xor(s2, s); s3 += __shfl_xor(s3, s);
            d0 += __shfl_xor(d0, s); d1 += __shfl_xor(d1, s);
            d2 += __shfl_xor(d2, s); d3 += __shfl_xor(d3, s);
        }
        if ((tt & 31) == 0) {
            const int hh = tt >> 5;
            ssa[hh][sub * 4 + 0] = s0 * L2E; ssa[hh][sub * 4 + 1] = s1 * L2E;
            ssa[hh][sub * 4 + 2] = s2 * L2E; ssa[hh][sub * 4 + 3] = s3 * L2E;
            ssd[hh][sub * 4 + 0] = d0 * L2E; ssd[hh][sub * 4 + 1] = d1 * L2E;
            ssd[hh][sub * 4 + 2] = d2 * L2E; ssd[hh][sub * 4 + 3] = d3 * L2E;
        }
        __syncthreads();
        if (t < 128)
            *reinterpret_cast<uint4*>(hpt + (size_t)t * N_NODES + i0) =
                *reinterpret_cast<const uint4*>(&hs[t * 4]);
        if (t < 64) {
            const int sd = t >> 5, hh = (t >> 3) & 3, nn = t & 7;
            const float v = sd ? ssd[hh][nn] : ssa[hh][nn];
            (sd ? adt : ast)[hh * N_NODES + i0 + nn] = v;
        }
    } else {
        __shared__ alignas(16) unsigned short lb[64 * 16];
        const int sblk  = blockIdx.x - HPB;
        const int strip = sblk & 63;
        const int chunk = sblk >> 6;
        const int c0    = strip * 64;
        const int r0    = chunk * 256;
        const int q     = t & 15;
        const int p     = t >> 4;
        const float4* adj4 = reinterpret_cast<const float4*>(adj);

        float4 v[16];
#pragma unroll
        for (int it = 0; it < 16; ++it)
            v[it] = adj4[(size_t)(r0 + p * 16 + it) * (N_NODES / 4) + (c0 >> 2) + q];
        unsigned mk0 = 0, mk1 = 0, mk2 = 0, mk3 = 0;
#pragma unroll
        for (int it = 0; it < 16; ++it) {
            mk0 |= (v[it].x != 0.f) ? (1u << it) : 0u;
            mk1 |= (v[it].y != 0.f) ? (1u << it) : 0u;
            mk2 |= (v[it].z != 0.f) ? (1u << it) : 0u;
            mk3 |= (v[it].w != 0.f) ? (1u << it) : 0u;
        }
        lb[(4 * q + 0) * 16 + p] = (unsigned short)mk0;
        lb[(4 * q + 1) * 16 + p] = (unsigned short)mk1;
        lb[(4 * q + 2) * 16 + p] = (unsigned short)mk2;
        lb[(4 * q + 3) * 16 + p] = (unsigned short)mk3;
        __syncthreads();
        const unsigned* lb32 = reinterpret_cast<const unsigned*>(lb);
#pragma unroll
        for (int j = 0; j < 2; ++j) {
            const int w = t + j * 256;
            const int m = w >> 3, col = w & 7;
            abits[(size_t)(c0 + m) * (N_NODES / 32) + chunk * 8 + col] = lb32[w];
        }
    }
}

// ---------------- kernel 2: barrier-free dense fused MFMA aggregation ----------------
// 1024 blocks (4/CU): 32 m-rows x 4 waves (wave=head) x 512-n split.
// No LDS staging for hp/bits: B-frags stream 16B/lane from L2-resident hpt;
// adjacency bits live in 4 uint4 regs per lane; ast broadcast from 8KB LDS.
// Zero in-loop barriers. tau via second MFMA against ones.
__global__ __launch_bounds__(256, 4)
void k_main(const unsigned short* __restrict__ hpt, const float* __restrict__ ast,
            const float* __restrict__ adt, const unsigned* __restrict__ abits,
            float* __restrict__ z_part, float* __restrict__ taup)
{
    __shared__ alignas(16) float as_s[HEADS * NRANGE];   // 8 KB
    const int t     = threadIdx.x;
    const int wv    = t >> 6;                  // head
    const int l     = t & 63;
    const int np    = l >> 5;
    const int lm    = l & 31;
    const int mt    = blockIdx.x >> 3;
    const int split = blockIdx.x & 7;
    const int m0    = mt * 32;
    const int nb0   = split * NRANGE;

    // stage as-slice once: [h][512] floats
    {
        const float4* src = reinterpret_cast<const float4*>(ast);
        float4* dst = reinterpret_cast<float4*>(as_s);
#pragma unroll
        for (int j = 0; j < 2; ++j) {
            const int lin = t * 2 + j;             // 0..511 float4s
            const int h   = lin >> 7;
            const int j4  = lin & 127;
            dst[lin] = src[h * (N_NODES / 4) + (nb0 >> 2) + j4];
        }
    }
    // adjacency bits for this lane's m-row: 64 B -> 4 uint4 regs
    uint4 brow[4];
    {
        const uint4* bsrc = reinterpret_cast<const uint4*>(
            abits + (size_t)(m0 + lm) * (N_NODES / 32) + split * 16);
#pragma unroll
        for (int j = 0; j < 4; ++j) brow[j] = bsrc[j];
    }
    const float adm = adt[wv * N_NODES + m0 + lm];
    __syncthreads();

    const unsigned short* hrow = hpt + (size_t)(wv * 32 + lm) * N_NODES + nb0 + np * 8;
    const float* asw = as_s + wv * NRANGE;

    float16v acc, acct;
#pragma unroll
    for (int r = 0; r < 16; ++r) { acc[r] = 0.f; acct[r] = 0.f; }
    union { short8v v; unsigned u[4]; } ones;
#pragma unroll
    for (int j = 0; j < 4; ++j) ones.u[j] = 0x3F803F80u;   // bf16 1.0 x2

#pragma unroll
    for (int step = 0; step < NSTEP; ++step) {
#pragma unroll
        for (int q = 0; q < 4; ++q) {
            // B-frag: 16B direct from L2-resident hpt
            const short8v bv = *reinterpret_cast<const short8v*>(hrow + step * 64 + q * 16);
            // as values: wave-uniform broadcast ds_read (conflict-free)
            const float4 a0 = *reinterpret_cast<const float4*>(asw + step * 64 + q * 16 + np * 8);
            const float4 a1 = *reinterpret_cast<const float4*>(asw + step * 64 + q * 16 + np * 8 + 4);
            // adjacency byte from regs (static indices: step/q compile-time)
            const unsigned w32 = (&brow[0].x)[((2 * step + (q >> 1)) & 15)];
            const unsigned bb  = (w32 >> (((q & 1) << 4) + (np << 3))) & 0xFFu;
            auto wq = [&](float a, unsigned bit) {
                const float c  = a + adm;
                const float ex = exp2f(fmaxf(0.2f * c, c));
                return (bb & bit) ? ex : 0.f;
            };
            const float w0 = wq(a0.x, 1u),  w1 = wq(a0.y, 2u);
            const float w2 = wq(a0.z, 4u),  w3 = wq(a0.w, 8u);
            const float w4 = wq(a1.x, 16u), w5 = wq(a1.y, 32u);
            const float w6 = wq(a1.z, 64u), w7 = wq(a1.w, 128u);
            union { short8v v; unsigned u[4]; } af;
            af.u[0] = cvt_pk_bf16(w0, w1);
            af.u[1] = cvt_pk_bf16(w2, w3);
            af.u[2] = cvt_pk_bf16(w4, w5);
            af.u[3] = cvt_pk_bf16(w6, w7);
            acc  = __builtin_amdgcn_mfma_f32_32x32x16_bf16(af.v, bv, acc, 0, 0, 0);
            acct = __builtin_amdgcn_mfma_f32_32x32x16_bf16(af.v, ones.v, acct, 0, 0, 0);
        }
    }

    // tau: every col of acct holds the row-sum; lanes lm==0 (np=0,1) cover 32 rows
    if (lm == 0) {
#pragma unroll
        for (int r = 0; r < 16; ++r) {
            const int row = (r & 3) + 8 * (r >> 2) + 4 * np;
            taup[((size_t)split * HEADS + wv) * N_NODES + m0 + row] = acct[r];
        }
    }
    float* zp = z_part + (size_t)split * N_NODES * FTOT;
#pragma unroll
    for (int r = 0; r < 16; ++r) {
        const int row = (r & 3) + 8 * (r >> 2) + 4 * np;
        zp[(size_t)(m0 + row) * FTOT + wv * 32 + lm] = acc[r];
    }
}

// ---------------- kernel 3: merge splits, divide by tau, add bias ----------------
__global__ __launch_bounds__(256)
void k_fin(const float* __restrict__ z_part, const float* __restrict__ taup,
           const float* __restrict__ bias, float* __restrict__ out)
{
    const int idx = blockIdx.x * 256 + threadIdx.x;
    const int m = idx >> 5, f4 = idx & 31, h = f4 >> 3;
    const float4* zp4 = reinterpret_cast<const float4*>(z_part);
    float4 z = make_float4(0.f, 0.f, 0.f, 0.f);
    float ts = 0.f;
#pragma unroll
    for (int s = 0; s < NSPLIT; ++s) {
        const float4 zs = zp4[(size_t)s * N_NODES * (FTOT / 4) + idx];
        z.x += zs.x; z.y += zs.y; z.z += zs.z; z.w += zs.w;
        ts += taup[((size_t)s * HEADS + h) * N_NODES + m];
    }
    const float inv = 1.f / ts;
    const float4 b = reinterpret_cast<const float4*>(bias)[f4];
    float4 o;
    o.x = z.x * inv + b.x; o.y = z.y * inv + b.y;
    o.z = z.z * inv + b.z; o.w = z.w * inv + b.w;
    reinterpret_cast<float4*>(out)[idx] = o;
}

extern "C" void kernel_launch(void* const* d_in, const int* in_sizes, int n_in,
                              void* d_out, int out_size, void* d_ws, size_t ws_size,
                              hipStream_t stream) {
    const float* x       = (const float*)d_in[0];
    const float* adj     = (const float*)d_in[1];
    const float* weight  = (const float*)d_in[2];
    const float* att_src = (const float*)d_in[3];
    const float* att_dst = (const float*)d_in[4];
    const float* bias    = (const float*)d_in[5];
    float* out = (float*)d_out;

    unsigned short* hpt = (unsigned short*)d_ws;
    float* ast = (float*)(hpt + (size_t)FTOT * N_NODES);
    float* adt = ast + (size_t)HEADS * N_NODES;
    unsigned* abits = (unsigned*)(adt + (size_t)HEADS * N_NODES);
    float* z_part = (float*)(abits + (size_t)N_NODES * (N_NODES / 32));
    float* taup = z_part + (size_t)NSPLIT * N_NODES * FTOT;

    k_pre <<<HPB + BITB, 256, 0, stream>>>(x, weight, att_src, att_dst, adj,
                                           hpt, ast, adt, abits);
    k_main<<<(N_NODES / 32) * NSPLIT, 256, 0, stream>>>(hpt, ast, adt, abits,
                                                        z_part, taup);
    k_fin <<<N_NODES * (FTOT / 4) / 256, 256, 0, stream>>>(z_part, taup, bias, out);
}

// Round 12
// 47.177 us; speedup vs baseline: 1.5145x; 1.1510x over previous
//
#include <hip/hip_runtime.h>
#include <hip/hip_bf16.h>

#define N_NODES 4096
#define F_IN    128
#define HEADS   4
#define FTOT    128
#define NSPLIT  8
#define NRANGE  (N_NODES / NSPLIT)   // 512
#define NSTEP   (NRANGE / 64)        // 8
#define HPB     512
#define BITB    1024
#define L2E     1.4426950408889634f

typedef __attribute__((ext_vector_type(8)))  short  short8v;
typedef __attribute__((ext_vector_type(16))) float  float16v;

static __device__ __forceinline__ unsigned f2bfu(float f) {
    union { __hip_bfloat16 h; unsigned short u; } cv;
    cv.h = __float2bfloat16(f);
    return (unsigned)cv.u;
}
static __device__ __forceinline__ unsigned cvt_pk_bf16(float lo, float hi) {
    unsigned r;
    asm("v_cvt_pk_bf16_f32 %0, %1, %2" : "=v"(r) : "v"(lo), "v"(hi));
    return r;
}

// ---------------- kernel 1: heterogeneous pre-pass (unchanged, verified) ----------------
__global__ __launch_bounds__(256)
void k_pre(const float* __restrict__ x, const float* __restrict__ W,
           const float* __restrict__ att_src, const float* __restrict__ att_dst,
           const float* __restrict__ adj,
           unsigned short* __restrict__ hpt, float* __restrict__ ast,
           float* __restrict__ adt, unsigned* __restrict__ abits)
{
    const int t = threadIdx.x;
    if (blockIdx.x < HPB) {
        __shared__ alignas(16) float    xs[8 * F_IN];
        __shared__ alignas(16) unsigned hs[F_IN * 4];
        __shared__ float ssa[4][8], ssd[4][8];
        const int sub = t >> 7;
        const int tt  = t & 127;
        const int i0  = blockIdx.x * 8;
        reinterpret_cast<float4*>(xs)[t] =
            reinterpret_cast<const float4*>(x + (size_t)i0 * F_IN)[t];
        __syncthreads();

        const float4* W4  = reinterpret_cast<const float4*>(W + tt * F_IN);
        const float4* xs4 = reinterpret_cast<const float4*>(xs + sub * 4 * F_IN);
        float a0 = 0.f, a1 = 0.f, a2 = 0.f, a3 = 0.f;
#pragma unroll
        for (int k = 0; k < F_IN / 4; ++k) {
            const float4 w  = W4[k];
            const float4 v0 = xs4[k], v1 = xs4[32 + k], v2 = xs4[64 + k], v3 = xs4[96 + k];
            a0 = fmaf(w.x, v0.x, a0); a0 = fmaf(w.y, v0.y, a0); a0 = fmaf(w.z, v0.z, a0); a0 = fmaf(w.w, v0.w, a0);
            a1 = fmaf(w.x, v1.x, a1); a1 = fmaf(w.y, v1.y, a1); a1 = fmaf(w.z, v1.z, a1); a1 = fmaf(w.w, v1.w, a1);
            a2 = fmaf(w.x, v2.x, a2); a2 = fmaf(w.y, v2.y, a2); a2 = fmaf(w.z, v2.z, a2); a2 = fmaf(w.w, v2.w, a2);
            a3 = fmaf(w.x, v3.x, a3); a3 = fmaf(w.y, v3.y, a3); a3 = fmaf(w.z, v3.z, a3); a3 = fmaf(w.w, v3.w, a3);
        }
        hs[tt * 4 + sub * 2 + 0] = f2bfu(a0) | (f2bfu(a1) << 16);
        hs[tt * 4 + sub * 2 + 1] = f2bfu(a2) | (f2bfu(a3) << 16);

        const float asv = att_src[tt], adv = att_dst[tt];
        float s0 = a0 * asv, s1 = a1 * asv, s2 = a2 * asv, s3 = a3 * asv;
        float d0 = a0 * adv, d1 = a1 * adv, d2 = a2 * adv, d3 = a3 * adv;
#pragma unroll
        for (int s = 16; s; s >>= 1) {
            s0 += __shfl_xor(s0, s); s1 += __shfl_xor(s1, s);
            s2 += __shfl_xor(s2, s); s3 += __shfl_xor(s3, s);
            d0 += __shfl_xor(d0, s); d1 += __shfl_xor(d1, s);
            d2 += __shfl_xor(d2, s); d3 += __shfl_xor(d3, s);
        }
        if ((tt & 31) == 0) {
            const int hh = tt >> 5;
            ssa[hh][sub * 4 + 0] = s0 * L2E; ssa[hh][sub * 4 + 1] = s1 * L2E;
            ssa[hh][sub * 4 + 2] = s2 * L2E; ssa[hh][sub * 4 + 3] = s3 * L2E;
            ssd[hh][sub * 4 + 0] = d0 * L2E; ssd[hh][sub * 4 + 1] = d1 * L2E;
            ssd[hh][sub * 4 + 2] = d2 * L2E; ssd[hh][sub * 4 + 3] = d3 * L2E;
        }
        __syncthreads();
        if (t < 128)
            *reinterpret_cast<uint4*>(hpt + (size_t)t * N_NODES + i0) =
                *reinterpret_cast<const uint4*>(&hs[t * 4]);
        if (t < 64) {
            const int sd = t >> 5, hh = (t >> 3) & 3, nn = t & 7;
            const float v = sd ? ssd[hh][nn] : ssa[hh][nn];
            (sd ? adt : ast)[hh * N_NODES + i0 + nn] = v;
        }
    } else {
        __shared__ alignas(16) unsigned short lb[64 * 16];
        const int sblk  = blockIdx.x - HPB;
        const int strip = sblk & 63;
        const int chunk = sblk >> 6;
        const int c0    = strip * 64;
        const int r0    = chunk * 256;
        const int q     = t & 15;
        const int p     = t >> 4;
        const float4* adj4 = reinterpret_cast<const float4*>(adj);

        float4 v[16];
#pragma unroll
        for (int it = 0; it < 16; ++it)
            v[it] = adj4[(size_t)(r0 + p * 16 + it) * (N_NODES / 4) + (c0 >> 2) + q];
        unsigned mk0 = 0, mk1 = 0, mk2 = 0, mk3 = 0;
#pragma unroll
        for (int it = 0; it < 16; ++it) {
            mk0 |= (v[it].x != 0.f) ? (1u << it) : 0u;
            mk1 |= (v[it].y != 0.f) ? (1u << it) : 0u;
            mk2 |= (v[it].z != 0.f) ? (1u << it) : 0u;
            mk3 |= (v[it].w != 0.f) ? (1u << it) : 0u;
        }
        lb[(4 * q + 0) * 16 + p] = (unsigned short)mk0;
        lb[(4 * q + 1) * 16 + p] = (unsigned short)mk1;
        lb[(4 * q + 2) * 16 + p] = (unsigned short)mk2;
        lb[(4 * q + 3) * 16 + p] = (unsigned short)mk3;
        __syncthreads();
        const unsigned* lb32 = reinterpret_cast<const unsigned*>(lb);
#pragma unroll
        for (int j = 0; j < 2; ++j) {
            const int w = t + j * 256;
            const int m = w >> 3, col = w & 7;
            abits[(size_t)(c0 + m) * (N_NODES / 32) + chunk * 8 + col] = lb32[w];
        }
    }
}

// ---------------- kernel 2: barrier-free, transcendental-free fused MFMA ----------------
// w[m][n] = adj * (p1>1 ? p1 : p2), p1 = EA1[n]*ED1[m], p2 = EA2[n]*ED2[m]
// (exp(lrelu(as+ad)) factorized; branch test c>0 <=> exp(c)>1).
// EA tables in 16KB LDS (broadcast reads); ED are 2 per-lane scalars.
// B-frags double-buffered in regs from L2-resident hpt. Zero in-loop barriers.
__global__ __launch_bounds__(256, 4)
void k_main(const unsigned short* __restrict__ hpt, const float* __restrict__ ast,
            const float* __restrict__ adt, const unsigned* __restrict__ abits,
            float* __restrict__ z_part, float* __restrict__ taup)
{
    __shared__ alignas(16) float2 ea_s[HEADS * NRANGE];   // 16 KB
    const int t     = threadIdx.x;
    const int wv    = t >> 6;                  // head
    const int l     = t & 63;
    const int np    = l >> 5;
    const int lm    = l & 31;
    const int mt    = blockIdx.x >> 3;
    const int split = blockIdx.x & 7;
    const int m0    = mt * 32;
    const int nb0   = split * NRANGE;

    // stage EA tables: EA1 = exp2(as'), EA2 = exp2(0.2 as')  (as' prescaled by log2e)
#pragma unroll
    for (int j = 0; j < 8; ++j) {
        const int lin = j * 256 + t;           // 0..2047
        const int h   = lin >> 9;
        const int n   = lin & 511;
        const float a = ast[h * N_NODES + nb0 + n];
        ea_s[lin] = make_float2(__builtin_amdgcn_exp2f(a),
                                __builtin_amdgcn_exp2f(0.2f * a));
    }
    // adjacency bits for this lane's m-row: 64 B -> 4 uint4 regs
    uint4 brow[4];
    {
        const uint4* bsrc = reinterpret_cast<const uint4*>(
            abits + (size_t)(m0 + lm) * (N_NODES / 32) + split * 16);
#pragma unroll
        for (int j = 0; j < 4; ++j) brow[j] = bsrc[j];
    }
    const float adm = adt[wv * N_NODES + m0 + lm];
    const float ed1 = __builtin_amdgcn_exp2f(adm);
    const float ed2 = __builtin_amdgcn_exp2f(0.2f * adm);
    __syncthreads();

    const unsigned short* hrow = hpt + (size_t)(wv * 32 + lm) * N_NODES + nb0 + np * 8;
    const float2* eaw = ea_s + wv * NRANGE;

    float16v acc, acct;
#pragma unroll
    for (int r = 0; r < 16; ++r) { acc[r] = 0.f; acct[r] = 0.f; }
    union { short8v v; unsigned u[4]; } ones;
#pragma unroll
    for (int j = 0; j < 4; ++j) ones.u[j] = 0x3F803F80u;   // bf16 1.0 x2

    short8v cur[4], nxt[4];
#pragma unroll
    for (int q = 0; q < 4; ++q)
        cur[q] = *reinterpret_cast<const short8v*>(hrow + q * 16);

#pragma unroll
    for (int step = 0; step < NSTEP; ++step) {
        if (step + 1 < NSTEP) {
#pragma unroll
            for (int q = 0; q < 4; ++q)
                nxt[q] = *reinterpret_cast<const short8v*>(hrow + (step + 1) * 64 + q * 16);
        }
#pragma unroll
        for (int q = 0; q < 4; ++q) {
            const float2* eap = eaw + step * 64 + q * 16 + np * 8;
            const unsigned w32 = (&brow[0].x)[((2 * step + (q >> 1)) & 15)];
            const unsigned bb  = (w32 >> (((q & 1) << 4) + (np << 3))) & 0xFFu;
            float w[8];
#pragma unroll
            for (int i = 0; i < 8; ++i) {
                const float2 e = eap[i];
                const float p1 = e.x * ed1;
                const float p2 = e.y * ed2;
                const float sel = (p1 > 1.0f) ? p1 : p2;
                w[i] = (bb & (1u << i)) ? sel : 0.f;
            }
            union { short8v v; unsigned u[4]; } af;
            af.u[0] = cvt_pk_bf16(w[0], w[1]);
            af.u[1] = cvt_pk_bf16(w[2], w[3]);
            af.u[2] = cvt_pk_bf16(w[4], w[5]);
            af.u[3] = cvt_pk_bf16(w[6], w[7]);
            acc  = __builtin_amdgcn_mfma_f32_32x32x16_bf16(af.v, cur[q], acc, 0, 0, 0);
            acct = __builtin_amdgcn_mfma_f32_32x32x16_bf16(af.v, ones.v, acct, 0, 0, 0);
        }
#pragma unroll
        for (int q = 0; q < 4; ++q) cur[q] = nxt[q];
    }

    // tau: every col of acct holds the row-sum; lanes lm==0 (np=0,1) cover 32 rows
    if (lm == 0) {
#pragma unroll
        for (int r = 0; r < 16; ++r) {
            const int row = (r & 3) + 8 * (r >> 2) + 4 * np;
            taup[((size_t)split * HEADS + wv) * N_NODES + m0 + row] = acct[r];
        }
    }
    float* zp = z_part + (size_t)split * N_NODES * FTOT;
#pragma unroll
    for (int r = 0; r < 16; ++r) {
        const int row = (r & 3) + 8 * (r >> 2) + 4 * np;
        zp[(size_t)(m0 + row) * FTOT + wv * 32 + lm] = acc[r];
    }
}

// ---------------- kernel 3: merge splits, divide by tau, add bias ----------------
__global__ __launch_bounds__(256)
void k_fin(const float* __restrict__ z_part, const float* __restrict__ taup,
           const float* __restrict__ bias, float* __restrict__ out)
{
    const int idx = blockIdx.x * 256 + threadIdx.x;
    const int m = idx >> 5, f4 = idx & 31, h = f4 >> 3;
    const float4* zp4 = reinterpret_cast<const float4*>(z_part);
    float4 z = make_float4(0.f, 0.f, 0.f, 0.f);
    float ts = 0.f;
#pragma unroll
    for (int s = 0; s < NSPLIT; ++s) {
        const float4 zs = zp4[(size_t)s * N_NODES * (FTOT / 4) + idx];
        z.x += zs.x; z.y += zs.y; z.z += zs.z; z.w += zs.w;
        ts += taup[((size_t)s * HEADS + h) * N_NODES + m];
    }
    const float inv = 1.f / ts;
    const float4 b = reinterpret_cast<const float4*>(bias)[f4];
    float4 o;
    o.x = z.x * inv + b.x; o.y = z.y * inv + b.y;
    o.z = z.z * inv + b.z; o.w = z.w * inv + b.w;
    reinterpret_cast<float4*>(out)[idx] = o;
}

extern "C" void kernel_launch(void* const* d_in, const int* in_sizes, int n_in,
                              void* d_out, int out_size, void* d_ws, size_t ws_size,
                              hipStream_t stream) {
    const float* x       = (const float*)d_in[0];
    const float* adj     = (const float*)d_in[1];
    const float* weight  = (const float*)d_in[2];
    const float* att_src = (const float*)d_in[3];
    const float* att_dst = (const float*)d_in[4];
    const float* bias    = (const float*)d_in[5];
    float* out = (float*)d_out;

    unsigned short* hpt = (unsigned short*)d_ws;
    float* ast = (float*)(hpt + (size_t)FTOT * N_NODES);
    float* adt = ast + (size_t)HEADS * N_NODES;
    unsigned* abits = (unsigned*)(adt + (size_t)HEADS * N_NODES);
    float* z_part = (float*)(abits + (size_t)N_NODES * (N_NODES / 32));
    float* taup = z_part + (size_t)NSPLIT * N_NODES * FTOT;

    k_pre <<<HPB + BITB, 256, 0, stream>>>(x, weight, att_src, att_dst, adj,
                                           hpt, ast, adt, abits);
    k_main<<<(N_NODES / 32) * NSPLIT, 256, 0, stream>>>(hpt, ast, adt, abits,
                                                        z_part, taup);
    k_fin <<<N_NODES * (FTOT / 4) / 256, 256, 0, stream>>>(z_part, taup, bias, out);
}